// Round 11
// baseline (213.578 us; speedup 1.0000x reference)
//
#include <hip/hip_runtime.h>
#include <math.h>

#define NN 50000
#define NE 800000
#define NBUCK 98            // bucket = dst >> 9 (512 nodes/bucket)
#define BSH 9
#define CAP 16384           // per-bucket capacity (mean 8192, max ~8650)
#define CHUNK 4096          // edges per block in bscatter
#define NCH ((NE + CHUNK - 1) / CHUNK)   // 196
#define EPT 16              // edges per thread (CHUNK/256)
#define GSZ 16              // gathers per node per round

typedef float4 f4;
typedef float2 f2;
typedef unsigned short u16;
typedef unsigned int u32;

__device__ __forceinline__ float sigf(float x) {
    // fast sigmoid: v_mul+v_exp+v_add+v_rcp (rcp ~1ulp; threshold 0.02)
    return __builtin_amdgcn_rcpf(1.0f + __expf(-x));
}

__device__ __forceinline__ u16 f32_to_bf16_rne(float f) {
    unsigned u = __float_as_uint(f);
    u += 0x7FFFu + ((u >> 16) & 1u);
    return (u16)(u >> 16);
}

// ---------------- K1: C = sig(z@Wc^T+bc); P = z@W1^T+bn; Qh = bf16(z@W2^T) ---
#define K1_WFLOATS (3 * 32 * 64 * 2)           // 12288 floats = 48KB
__global__ __launch_bounds__(512, 4) void k1_node(
    const float* __restrict__ z,
    const float* __restrict__ Wc, const float* __restrict__ bc,
    const float* __restrict__ Wn, const float* __restrict__ bn,
    float* __restrict__ P, u16* __restrict__ Qh, float* __restrict__ C,
    int* __restrict__ gcur)
{
    if (blockIdx.x == 0 && threadIdx.x < 128) gcur[threadIdx.x] = 0;

    __shared__ float sh[K1_WFLOATS + 8 * 256];  // 48KB weights + 8KB tiles
    const int tid = threadIdx.x;
    f2* w2 = (f2*)sh;
    for (int j = tid; j < 3 * 32 * 64; j += 512) {
        const int m = j >> 11, r = j & 2047;
        const int k2 = r >> 6, h = r & 63;
        const float* s = (m == 0) ? (Wc + h * 64 + 2 * k2)
                                  : (Wn + h * 128 + (m - 1) * 64 + 2 * k2);
        w2[(m * 32 + k2) * 64 + h] = *(const f2*)s;
    }
    __syncthreads();

    const int lane = tid & 63;
    const int wid  = tid >> 6;
    f4* tile = (f4*)(sh + K1_WFLOATS) + wid * 64;
    const f2* wl0 = w2;
    const f2* wl1 = w2 + 32 * 64;
    const f2* wl2 = w2 + 2 * 32 * 64;
    const float bcur = bc[lane], bnbr = bn[lane];

    const int gw = blockIdx.x * 8 + wid;
    const int nw = gridDim.x * 8;
    for (int chunk = gw; chunk < NN / 4; chunk += nw) {
        const int n0 = chunk * 4;
        tile[lane] = *(const f4*)(z + n0 * 64 + lane * 4);  // wave-private stage
        float a0[4], a1[4], a2[4];
        #pragma unroll
        for (int ni = 0; ni < 4; ++ni) { a0[ni] = 0.f; a1[ni] = 0.f; a2[ni] = 0.f; }
        #pragma unroll 2
        for (int k4 = 0; k4 < 16; ++k4) {
            const f2 w0a = wl0[(2 * k4) * 64 + lane], w0b = wl0[(2 * k4 + 1) * 64 + lane];
            const f2 w1a = wl1[(2 * k4) * 64 + lane], w1b = wl1[(2 * k4 + 1) * 64 + lane];
            const f2 w2a = wl2[(2 * k4) * 64 + lane], w2b = wl2[(2 * k4 + 1) * 64 + lane];
            #pragma unroll
            for (int ni = 0; ni < 4; ++ni) {
                const f4 zz = tile[ni * 16 + k4];  // uniform addr -> LDS broadcast
                a0[ni] = fmaf(w0b.y, zz.w, fmaf(w0b.x, zz.z, fmaf(w0a.y, zz.y, fmaf(w0a.x, zz.x, a0[ni]))));
                a1[ni] = fmaf(w1b.y, zz.w, fmaf(w1b.x, zz.z, fmaf(w1a.y, zz.y, fmaf(w1a.x, zz.x, a1[ni]))));
                a2[ni] = fmaf(w2b.y, zz.w, fmaf(w2b.x, zz.z, fmaf(w2a.y, zz.y, fmaf(w2a.x, zz.x, a2[ni]))));
            }
        }
        #pragma unroll
        for (int ni = 0; ni < 4; ++ni) {
            const int n = n0 + ni;
            C[n * 64 + lane]  = sigf(a0[ni] + bcur);
            P[n * 64 + lane]  = a1[ni] + bnbr;
            Qh[n * 64 + lane] = f32_to_bf16_rne(a2[ni]);
        }
    }
}

// ---------------- Bucketed CSR build (fixed-capacity, no global scan) -------
__global__ __launch_bounds__(256) void k_bscatter(const int* __restrict__ esrc,
                                                  const int* __restrict__ edst,
                                                  int* __restrict__ gcur,
                                                  u32* __restrict__ ebuf)
{
    __shared__ int cnt[NBUCK];
    __shared__ int gbase[NBUCK];
    __shared__ int lcur[NBUCK];
    for (int i = threadIdx.x; i < NBUCK; i += 256) cnt[i] = 0;
    __syncthreads();

    const int base = blockIdx.x * CHUNK;
    u32 ent[EPT];
    int nb[EPT];
    #pragma unroll
    for (int t = 0; t < EPT; ++t) {
        const int e = base + t * 256 + threadIdx.x;
        if (e < NE) {
            const int d = edst[e], s = esrc[e];
            const int b = d >> BSH;
            ent[t] = ((u32)(d & 511) << 16) | (u32)s;
            nb[t] = b;
            atomicAdd(&cnt[b], 1);
        } else {
            nb[t] = -1;
        }
    }
    __syncthreads();
    for (int i = threadIdx.x; i < NBUCK; i += 256) {
        gbase[i] = cnt[i] ? atomicAdd(&gcur[i], cnt[i]) : 0;
        lcur[i] = 0;
    }
    __syncthreads();
    #pragma unroll
    for (int t = 0; t < EPT; ++t) {
        if (nb[t] >= 0) {
            const int li = atomicAdd(&lcur[nb[t]], 1);
            ebuf[nb[t] * CAP + gbase[nb[t]] + li] = ent[t];
        }
    }
}

__global__ __launch_bounds__(256) void k_bsort(const int* __restrict__ gcur,
                                               const u32* __restrict__ ebuf,
                                               u32* __restrict__ bd,
                                               u16* __restrict__ ss)
{
    __shared__ int hist[512];
    __shared__ int lcur[512];
    __shared__ int ps[256];
    const int b = blockIdx.x;
    const int ecnt = gcur[b];
    const int e0 = b * CAP;
    const int n0 = b << BSH;
    const int t = threadIdx.x;

    hist[t] = 0; hist[t + 256] = 0;
    __syncthreads();
    for (int j = t; j < ecnt; j += 256)
        atomicAdd(&hist[(ebuf[e0 + j] >> 16) & 511], 1);
    __syncthreads();
    const int a0 = hist[2 * t], a1 = hist[2 * t + 1];
    ps[t] = a0 + a1;
    __syncthreads();
    for (int o = 1; o < 256; o <<= 1) {
        int v = 0;
        if (t >= o) v = ps[t - o];
        __syncthreads();
        if (t >= o) ps[t] += v;
        __syncthreads();
    }
    const int excl = (t > 0) ? ps[t - 1] : 0;
    lcur[2 * t] = excl;
    lcur[2 * t + 1] = excl + a0;
    const int nA = n0 + 2 * t, nB = n0 + 2 * t + 1;
    if (nA < NN) bd[nA] = ((u32)(e0 + excl) << 8) | (u32)a0;
    if (nB < NN) bd[nB] = ((u32)(e0 + excl + a0) << 8) | (u32)a1;
    __syncthreads();
    for (int j = t; j < ecnt; j += 256) {
        const u32 ent = ebuf[e0 + j];
        const int p = atomicAdd(&lcur[(ent >> 16) & 511], 1);
        ss[e0 + p] = (u16)(ent & 0xFFFFu);
    }
}

// 16 forced-in-flight bf16 gathers (asm issue order; results all live).
__device__ __forceinline__ void gather16(const u16* __restrict__ qbl,
                                         const u16* __restrict__ ss,
                                         int beg, int jb, int cap,
                                         u32 (&q)[GSZ])
{
    #pragma unroll
    for (int t = 0; t < GSZ; ++t) {
        int idx = jb + t;
        idx = idx < cap ? idx : cap;                 // clamp (dup line = cheap)
        const u16* ap = qbl + (((int)ss[beg + idx]) << 6);
        asm volatile("global_load_ushort %0, %1, off" : "=v"(q[t]) : "v"(ap));
    }
}

// ---------------- Fused K2+K3: one wave per 4 dst nodes ---------------------
// Per round: 64 asm-forced gathers (4 nodes x 16) in flight -> one vmcnt(0).
// k3 contraction amortizes Wo LDS reads over 4 nodes.
#define KF_WFLOATS (64 * 64 * 2)               // Wo: 8192 floats = 32KB
__global__ __launch_bounds__(512) void k2k3(
    const u32* __restrict__ bd, const u16* __restrict__ ss,
    const float* __restrict__ P, const u16* __restrict__ Qh,
    const float* __restrict__ C, const float* __restrict__ Wo,
    const float* __restrict__ bo, float* __restrict__ out)
{
    __shared__ float sh[KF_WFLOATS + 8 * 512];  // 32KB Wo + 16KB tiles = 48KB
    const int tid = threadIdx.x;
    f2* w2 = (f2*)sh;
    for (int j = tid; j < 64 * 64; j += 512) {
        const int k2 = j >> 6, d = j & 63;
        w2[k2 * 64 + d] = *(const f2*)(Wo + d * 128 + 2 * k2);
    }
    __syncthreads();

    const int lane = tid & 63;
    const int wid  = tid >> 6;
    float* tile = sh + KF_WFLOATS + wid * 512;  // [4 nodes][C row | NB row]
    const f4* t4 = (const f4*)tile;
    const u16* qbl = Qh + lane;
    const float bout = bo[lane];

    for (int chunk = blockIdx.x * 8 + wid; chunk < NN / 4; chunk += gridDim.x * 8) {
        const int n0 = chunk * 4;
        int beg[4], dg[4], cap[4];
        float p[4], acc[4];
        #pragma unroll
        for (int i = 0; i < 4; ++i) {
            const u32 w = bd[n0 + i];           // wave-uniform
            beg[i] = __builtin_amdgcn_readfirstlane((int)(w >> 8));
            dg[i]  = __builtin_amdgcn_readfirstlane((int)(w & 255u));
            cap[i] = dg[i] > 0 ? dg[i] - 1 : 0;
            p[i]   = P[(n0 + i) * 64 + lane];
            tile[i * 128 + lane] = C[(n0 + i) * 64 + lane];
            acc[i] = 0.f;
        }

        int jb = 0;
        while (true) {
            u32 q0[GSZ], q1[GSZ], q2[GSZ], q3[GSZ];
            gather16(qbl, ss, beg[0], jb, cap[0], q0);
            gather16(qbl, ss, beg[1], jb, cap[1], q1);
            gather16(qbl, ss, beg[2], jb, cap[2], q2);
            gather16(qbl, ss, beg[3], jb, cap[3], q3);
            asm volatile("s_waitcnt vmcnt(0)" ::: "memory");
            __builtin_amdgcn_sched_barrier(0);
            #pragma unroll
            for (int t = 0; t < GSZ; ++t) {
                const float m0 = sigf(p[0] + __uint_as_float(q0[t] << 16));
                const float m1 = sigf(p[1] + __uint_as_float(q1[t] << 16));
                const float m2 = sigf(p[2] + __uint_as_float(q2[t] << 16));
                const float m3 = sigf(p[3] + __uint_as_float(q3[t] << 16));
                acc[0] += (jb + t < dg[0]) ? m0 : 0.f;
                acc[1] += (jb + t < dg[1]) ? m1 : 0.f;
                acc[2] += (jb + t < dg[2]) ? m2 : 0.f;
                acc[3] += (jb + t < dg[3]) ? m3 : 0.f;
            }
            jb += GSZ;
            if (!(jb < dg[0] || jb < dg[1] || jb < dg[2] || jb < dg[3])) break;
        }

        #pragma unroll
        for (int i = 0; i < 4; ++i)
            tile[i * 128 + 64 + lane] = acc[i];  // wave-internal: no barrier

        float a2[4] = {0.f, 0.f, 0.f, 0.f};
        #pragma unroll 2
        for (int k4 = 0; k4 < 32; ++k4) {
            const f2 wa = w2[(2 * k4) * 64 + lane];
            const f2 wb = w2[(2 * k4 + 1) * 64 + lane];
            #pragma unroll
            for (int i = 0; i < 4; ++i) {
                const f4 hv = t4[i * 32 + k4];  // uniform addr -> LDS broadcast
                a2[i] = fmaf(wb.y, hv.w, fmaf(wb.x, hv.z, fmaf(wa.y, hv.y, fmaf(wa.x, hv.x, a2[i]))));
            }
        }
        #pragma unroll
        for (int i = 0; i < 4; ++i)
            out[(n0 + i) * 64 + lane] = tanhf(a2[i] + bout);
    }
}

extern "C" void kernel_launch(void* const* d_in, const int* in_sizes, int n_in,
                              void* d_out, int out_size, void* d_ws, size_t ws_size,
                              hipStream_t stream) {
    const float* z  = (const float*)d_in[0];
    const int* esrc = (const int*)d_in[1];
    const int* edst = (const int*)d_in[2];
    const float* Wc = (const float*)d_in[3];
    const float* bc = (const float*)d_in[4];
    const float* Wn = (const float*)d_in[5];
    const float* bn = (const float*)d_in[6];
    const float* Wo = (const float*)d_in[7];
    const float* bo = (const float*)d_in[8];
    float* out = (float*)d_out;

    float* P   = (float*)d_ws;                   // [NN*64] f32
    float* C   = P + (size_t)NN * 64;            // [NN*64] f32
    u16* Qh    = (u16*)(C + (size_t)NN * 64);    // [NN*64] bf16
    u32* bd    = (u32*)(Qh + (size_t)NN * 64);   // [NN] packed (beg<<8)|deg
    int* gcur  = (int*)(bd + NN + 64);           // [128]
    u32* ebuf  = (u32*)(gcur + 128);             // [NBUCK*CAP] packed entries
    u16* ss    = (u16*)(ebuf + (size_t)NBUCK * CAP); // [NBUCK*CAP + pad] u16

    k1_node<<<782, 512, 0, stream>>>(z, Wc, bc, Wn, bn, P, Qh, C, gcur);
    k_bscatter<<<NCH, 256, 0, stream>>>(esrc, edst, gcur, ebuf);
    k_bsort<<<NBUCK, 256, 0, stream>>>(gcur, ebuf, bd, ss);
    k2k3<<<1563, 512, 0, stream>>>(bd, ss, P, Qh, C, Wo, bo, out);
}

// Round 12
// 128.328 us; speedup vs baseline: 1.6643x; 1.6643x over previous
//
#include <hip/hip_runtime.h>
#include <math.h>

#define NN 50000
#define NE 800000
#define NBUCK 98            // bucket = dst >> 9 (512 nodes/bucket)
#define BSH 9
#define CAP 16384           // per-bucket capacity (entries); rounded totals <= ~12300
#define CHUNK 4096          // edges per block in bscatter
#define NCH ((NE + CHUNK - 1) / CHUNK)   // 196
#define EPT 16              // edges per thread (CHUNK/256)
#define GSZ 16              // gathers per node per round

typedef float4 f4;
typedef float2 f2;
typedef unsigned short u16;
typedef unsigned int u32;

__device__ __forceinline__ float sigf(float x) {
    return __builtin_amdgcn_rcpf(1.0f + __expf(-x));
}

__device__ __forceinline__ u16 f32_to_bf16_rne(float f) {
    unsigned u = __float_as_uint(f);
    u += 0x7FFFu + ((u >> 16) & 1u);
    return (u16)(u >> 16);
}

// ---------------- K1: C = sig(z@Wc^T+bc); P = z@W1^T+bn; Qh = bf16(z@W2^T) ---
#define K1_WFLOATS (3 * 32 * 64 * 2)           // 12288 floats = 48KB
__global__ __launch_bounds__(512, 4) void k1_node(
    const float* __restrict__ z,
    const float* __restrict__ Wc, const float* __restrict__ bc,
    const float* __restrict__ Wn, const float* __restrict__ bn,
    float* __restrict__ P, u16* __restrict__ Qh, float* __restrict__ C,
    int* __restrict__ gcur)
{
    if (blockIdx.x == 0 && threadIdx.x < 128) gcur[threadIdx.x] = 0;

    __shared__ float sh[K1_WFLOATS + 8 * 256];  // 48KB weights + 8KB tiles
    const int tid = threadIdx.x;
    f2* w2 = (f2*)sh;
    for (int j = tid; j < 3 * 32 * 64; j += 512) {
        const int m = j >> 11, r = j & 2047;
        const int k2 = r >> 6, h = r & 63;
        const float* s = (m == 0) ? (Wc + h * 64 + 2 * k2)
                                  : (Wn + h * 128 + (m - 1) * 64 + 2 * k2);
        w2[(m * 32 + k2) * 64 + h] = *(const f2*)s;
    }
    __syncthreads();

    const int lane = tid & 63;
    const int wid  = tid >> 6;
    f4* tile = (f4*)(sh + K1_WFLOATS) + wid * 64;
    const f2* wl0 = w2;
    const f2* wl1 = w2 + 32 * 64;
    const f2* wl2 = w2 + 2 * 32 * 64;
    const float bcur = bc[lane], bnbr = bn[lane];

    const int gw = blockIdx.x * 8 + wid;
    const int nw = gridDim.x * 8;
    for (int chunk = gw; chunk < NN / 4; chunk += nw) {
        const int n0 = chunk * 4;
        tile[lane] = *(const f4*)(z + n0 * 64 + lane * 4);  // wave-private stage
        float a0[4], a1[4], a2[4];
        #pragma unroll
        for (int ni = 0; ni < 4; ++ni) { a0[ni] = 0.f; a1[ni] = 0.f; a2[ni] = 0.f; }
        #pragma unroll 2
        for (int k4 = 0; k4 < 16; ++k4) {
            const f2 w0a = wl0[(2 * k4) * 64 + lane], w0b = wl0[(2 * k4 + 1) * 64 + lane];
            const f2 w1a = wl1[(2 * k4) * 64 + lane], w1b = wl1[(2 * k4 + 1) * 64 + lane];
            const f2 w2a = wl2[(2 * k4) * 64 + lane], w2b = wl2[(2 * k4 + 1) * 64 + lane];
            #pragma unroll
            for (int ni = 0; ni < 4; ++ni) {
                const f4 zz = tile[ni * 16 + k4];  // uniform addr -> LDS broadcast
                a0[ni] = fmaf(w0b.y, zz.w, fmaf(w0b.x, zz.z, fmaf(w0a.y, zz.y, fmaf(w0a.x, zz.x, a0[ni]))));
                a1[ni] = fmaf(w1b.y, zz.w, fmaf(w1b.x, zz.z, fmaf(w1a.y, zz.y, fmaf(w1a.x, zz.x, a1[ni]))));
                a2[ni] = fmaf(w2b.y, zz.w, fmaf(w2b.x, zz.z, fmaf(w2a.y, zz.y, fmaf(w2a.x, zz.x, a2[ni]))));
            }
        }
        #pragma unroll
        for (int ni = 0; ni < 4; ++ni) {
            const int n = n0 + ni;
            C[n * 64 + lane]  = sigf(a0[ni] + bcur);
            P[n * 64 + lane]  = a1[ni] + bnbr;
            Qh[n * 64 + lane] = f32_to_bf16_rne(a2[ni]);
        }
    }
}

// ---------------- Bucketed CSR build -----------------------------------------
__global__ __launch_bounds__(256) void k_bscatter(const int* __restrict__ esrc,
                                                  const int* __restrict__ edst,
                                                  int* __restrict__ gcur,
                                                  u32* __restrict__ ebuf)
{
    __shared__ int cnt[NBUCK];
    __shared__ int gbase[NBUCK];
    __shared__ int lcur[NBUCK];
    for (int i = threadIdx.x; i < NBUCK; i += 256) cnt[i] = 0;
    __syncthreads();

    const int base = blockIdx.x * CHUNK;
    u32 ent[EPT];
    int nb[EPT];
    #pragma unroll
    for (int t = 0; t < EPT; ++t) {
        const int e = base + t * 256 + threadIdx.x;
        if (e < NE) {
            const int d = edst[e], s = esrc[e];
            const int b = d >> BSH;
            ent[t] = ((u32)(d & 511) << 16) | (u32)s;
            nb[t] = b;
            atomicAdd(&cnt[b], 1);
        } else {
            nb[t] = -1;
        }
    }
    __syncthreads();
    for (int i = threadIdx.x; i < NBUCK; i += 256) {
        gbase[i] = cnt[i] ? atomicAdd(&gcur[i], cnt[i]) : 0;
        lcur[i] = 0;
    }
    __syncthreads();
    #pragma unroll
    for (int t = 0; t < EPT; ++t) {
        if (nb[t] >= 0) {
            const int li = atomicAdd(&lcur[nb[t]], 1);
            ebuf[nb[t] * CAP + gbase[nb[t]] + li] = ent[t];
        }
    }
}

// One block per bucket. Node segments rounded to 8 entries (16B) so k2 can
// use aligned uint4 index loads; pad entries zero-filled (gather node 0,
// contribution predicated off).
__global__ __launch_bounds__(256) void k_bsort(const int* __restrict__ gcur,
                                               const u32* __restrict__ ebuf,
                                               u32* __restrict__ bd,
                                               u16* __restrict__ ss)
{
    __shared__ int hist[512];
    __shared__ int lcur[512];
    __shared__ int ps[256];
    __shared__ int tot;
    const int b = blockIdx.x;
    const int ecnt = gcur[b];
    const int e0 = b * CAP;
    const int n0 = b << BSH;
    const int t = threadIdx.x;

    hist[t] = 0; hist[t + 256] = 0;
    __syncthreads();
    for (int j = t; j < ecnt; j += 256)
        atomicAdd(&hist[(ebuf[e0 + j] >> 16) & 511], 1);
    __syncthreads();
    const int a0 = hist[2 * t], a1 = hist[2 * t + 1];
    const int r0 = (a0 + 7) & ~7, r1 = (a1 + 7) & ~7;   // rounded slot sizes
    ps[t] = r0 + r1;
    __syncthreads();
    for (int o = 1; o < 256; o <<= 1) {
        int v = 0;
        if (t >= o) v = ps[t - o];
        __syncthreads();
        if (t >= o) ps[t] += v;
        __syncthreads();
    }
    const int excl = (t > 0) ? ps[t - 1] : 0;
    lcur[2 * t] = excl;
    lcur[2 * t + 1] = excl + r0;
    const int nA = n0 + 2 * t, nB = n0 + 2 * t + 1;
    if (nA < NN) bd[nA] = ((u32)(e0 + excl) << 8) | (u32)a0;
    if (nB < NN) bd[nB] = ((u32)(e0 + excl + r0) << 8) | (u32)a1;
    if (t == 255) tot = ps[255];
    __syncthreads();
    // zero-fill rounded region (+16 spill guard) before scatter
    const int zw = (tot + 16) >> 1;             // u32 words
    u32* ssw = (u32*)(ss + e0);
    for (int j = t; j < zw; j += 256) ssw[j] = 0;
    __syncthreads();
    for (int j = t; j < ecnt; j += 256) {
        const u32 ent = ebuf[e0 + j];
        const int p = atomicAdd(&lcur[(ent >> 16) & 511], 1);
        ss[e0 + p] = (u16)(ent & 0xFFFFu);
    }
}

// ---------------- K2: one wave per dst node, 16-deep forced gather MLP ------
// Per round: 2 aligned uint4 loads fetch 16 u16 indices (one wait), then 16
// asm global_load_ushort issue back-to-back (addresses all ready -> no
// intervening waits), one vmcnt(0) + sched_barrier(0), then VALU.
__global__ __launch_bounds__(256) void k2_agg(
    const u32* __restrict__ bd, const u16* __restrict__ ss,
    const float* __restrict__ P, const u16* __restrict__ Qh,
    float* __restrict__ NB)
{
    const int lane = threadIdx.x & 63;
    const int n = blockIdx.x * 4 + (threadIdx.x >> 6);
    if (n >= NN) return;
    const u32 w = bd[n];
    const int beg = __builtin_amdgcn_readfirstlane((int)(w >> 8));
    const int dg  = __builtin_amdgcn_readfirstlane((int)(w & 255u));
    const u16* qbl = Qh + lane;
    const float p = P[n * 64 + lane];
    float acc = 0.f;

    for (int jb = 0; jb < dg; jb += GSZ) {
        const uint4 iv0 = *(const uint4*)(ss + beg + jb);
        const uint4 iv1 = *(const uint4*)(ss + beg + jb + 8);
        const u32 wv[8] = {iv0.x, iv0.y, iv0.z, iv0.w, iv1.x, iv1.y, iv1.z, iv1.w};
        u32 q[GSZ];
        #pragma unroll
        for (int t8 = 0; t8 < 8; ++t8) {
            const u16* aL = qbl + ((wv[t8] & 0xFFFFu) << 6);
            const u16* aH = qbl + ((wv[t8] >> 16) << 6);
            asm volatile("global_load_ushort %0, %1, off" : "=v"(q[2 * t8])     : "v"(aL));
            asm volatile("global_load_ushort %0, %1, off" : "=v"(q[2 * t8 + 1]) : "v"(aH));
        }
        asm volatile("s_waitcnt vmcnt(0)" ::: "memory");
        __builtin_amdgcn_sched_barrier(0);
        #pragma unroll
        for (int t = 0; t < GSZ; ++t) {
            const float m = sigf(p + __uint_as_float(q[t] << 16));
            acc += (jb + t < dg) ? m : 0.f;
        }
    }
    NB[n * 64 + lane] = acc;
}

// ---------------- K3: out = tanh([C|NB] @ Wo^T + bo) -----------------------
#define K3_WFLOATS (64 * 64 * 2)               // 8192 floats = 32KB
__global__ __launch_bounds__(512, 4) void k3_out(
    const float* __restrict__ C, const float* __restrict__ NB,
    const float* __restrict__ Wo, const float* __restrict__ bo,
    float* __restrict__ out)
{
    __shared__ float sh[K3_WFLOATS + 8 * 512];  // 32KB weights + 16KB tiles
    const int tid = threadIdx.x;
    f2* w2 = (f2*)sh;
    for (int j = tid; j < 64 * 64; j += 512) {
        const int k2 = j >> 6, d = j & 63;
        w2[k2 * 64 + d] = *(const f2*)(Wo + d * 128 + 2 * k2);
    }
    __syncthreads();

    const int lane = tid & 63;
    const int wid  = tid >> 6;
    f4* tile = (f4*)(sh + K3_WFLOATS) + wid * 128;
    const float bout = bo[lane];

    const int gw = blockIdx.x * 8 + wid;
    const int nw = gridDim.x * 8;
    for (int chunk = gw; chunk < NN / 4; chunk += nw) {
        const int n0 = chunk * 4;
        #pragma unroll
        for (int tt = 0; tt < 2; ++tt) {
            const int j = lane + tt * 64;
            const int ni = j >> 5, q = j & 31;
            const float* src = (q < 16) ? (C + (n0 + ni) * 64 + q * 4)
                                        : (NB + (n0 + ni) * 64 + (q - 16) * 4);
            tile[ni * 32 + q] = *(const f4*)src;
        }
        float acc[4];
        #pragma unroll
        for (int ni = 0; ni < 4; ++ni) acc[ni] = 0.f;
        #pragma unroll 2
        for (int k4 = 0; k4 < 32; ++k4) {
            const f2 wa = w2[(2 * k4) * 64 + lane];
            const f2 wb = w2[(2 * k4 + 1) * 64 + lane];
            #pragma unroll
            for (int ni = 0; ni < 4; ++ni) {
                const f4 hv = tile[ni * 32 + k4];  // uniform addr -> broadcast
                acc[ni] = fmaf(wb.y, hv.w, fmaf(wb.x, hv.z, fmaf(wa.y, hv.y, fmaf(wa.x, hv.x, acc[ni]))));
            }
        }
        #pragma unroll
        for (int ni = 0; ni < 4; ++ni)
            out[(n0 + ni) * 64 + lane] = tanhf(acc[ni] + bout);
    }
}

extern "C" void kernel_launch(void* const* d_in, const int* in_sizes, int n_in,
                              void* d_out, int out_size, void* d_ws, size_t ws_size,
                              hipStream_t stream) {
    const float* z  = (const float*)d_in[0];
    const int* esrc = (const int*)d_in[1];
    const int* edst = (const int*)d_in[2];
    const float* Wc = (const float*)d_in[3];
    const float* bc = (const float*)d_in[4];
    const float* Wn = (const float*)d_in[5];
    const float* bn = (const float*)d_in[6];
    const float* Wo = (const float*)d_in[7];
    const float* bo = (const float*)d_in[8];
    float* out = (float*)d_out;

    float* P   = (float*)d_ws;                   // [NN*64] f32
    float* C   = P + (size_t)NN * 64;            // [NN*64] f32
    float* NB  = C + (size_t)NN * 64;            // [NN*64] f32
    u16* Qh    = (u16*)(NB + (size_t)NN * 64);   // [NN*64] bf16
    u32* bd    = (u32*)(Qh + (size_t)NN * 64);   // [NN] packed (beg<<8)|deg
    int* gcur  = (int*)(bd + NN + 64);           // [128]
    u32* ebuf  = (u32*)(gcur + 128);             // [NBUCK*CAP] packed entries
    u16* ss    = (u16*)(ebuf + (size_t)NBUCK * CAP); // [NBUCK*CAP + pad] u16

    k1_node<<<782, 512, 0, stream>>>(z, Wc, bc, Wn, bn, P, Qh, C, gcur);
    k_bscatter<<<NCH, 256, 0, stream>>>(esrc, edst, gcur, ebuf);
    k_bsort<<<NBUCK, 256, 0, stream>>>(gcur, ebuf, bd, ss);
    k2_agg<<<12500, 256, 0, stream>>>(bd, ss, P, Qh, NB);
    k3_out<<<782, 512, 0, stream>>>(C, NB, Wo, bo, out);
}